// Round 1
// 593.628 us; speedup vs baseline: 1.1169x; 1.1169x over previous
//
#include <hip/hip_runtime.h>

// Problem constants (AdditiveAttention): B=32, S=2048, HLEN=VLEN=HID=1024, fp32 in/out.
constexpr int B_   = 32;
constexpr int S_   = 2048;
constexpr int HID_ = 1024;
constexpr int VL_  = 1024;   // VLEN == HLEN == HID == 1024

typedef __attribute__((ext_vector_type(4))) float  f32x4;
typedef __attribute__((ext_vector_type(4))) short  s16x4;
typedef __attribute__((ext_vector_type(8))) short  s16x8;

// fp32 -> bf16 round-to-nearest-even
__device__ __forceinline__ short f2bf(float f) {
    union { float f; unsigned u; } v; v.f = f;
    unsigned r = v.u + 0x7fffu + ((v.u >> 16) & 1u);
    return (short)(r >> 16);
}

__device__ __forceinline__ float bf2f(short s) {
    union { unsigned u; float f; } v;
    v.u = ((unsigned)(unsigned short)s) << 16;
    return v.f;
}

__device__ __forceinline__ float fast_tanh(float x) {
    float e2 = __expf(2.0f * x);
    return 1.0f - 2.0f / (e2 + 1.0f);
}

// async 16B global->LDS DMA: per-lane global src, wave-uniform LDS base;
// lane i's data lands at ldsbase + i*16  [m97 / m104 semantics]
__device__ __forceinline__ void async_cp16(const void* g, void* l) {
    __builtin_amdgcn_global_load_lds(
        (const __attribute__((address_space(1))) unsigned int*)g,
        (__attribute__((address_space(3))) unsigned int*)l,
        16, 0, 0);
}

// ---------------- h_proj = h @ W_w^T + W_b  [B, HID] ----------------
__global__ __launch_bounds__(256) void hproj_kernel(const float* __restrict__ h,
                                                    const float* __restrict__ Ww,
                                                    const float* __restrict__ Wb,
                                                    float* __restrict__ hp) {
    int tid = threadIdx.x;
    int wave = tid >> 6, lane = tid & 63;
    int d = blockIdx.x * 4 + wave;   // grid.x = HID/4 = 256
    const float* wr = Ww + (size_t)d * HID_;
    float4 wreg[4];
#pragma unroll
    for (int i = 0; i < 4; i++) wreg[i] = *(const float4*)(wr + i * 256 + lane * 4);
    float bias = Wb[d];
    for (int b = 0; b < B_; b++) {
        const float* hr = h + (size_t)b * HID_;
        float acc = 0.0f;
#pragma unroll
        for (int i = 0; i < 4; i++) {
            float4 x = *(const float4*)(hr + i * 256 + lane * 4);
            acc += wreg[i].x * x.x + wreg[i].y * x.y + wreg[i].z * x.z + wreg[i].w * x.w;
        }
#pragma unroll
        for (int o = 32; o; o >>= 1) acc += __shfl_xor(acc, o);
        if (lane == 0) hp[(size_t)b * HID_ + d] = acc + bias;
    }
}

// ---------------- fp32 -> bf16 bulk convert (grid-stride over float4) ----------------
__global__ __launch_bounds__(256) void cvt_kernel(const float* __restrict__ src,
                                                  short* __restrict__ dst, size_t n4) {
    size_t i = (size_t)blockIdx.x * blockDim.x + threadIdx.x;
    size_t stride = (size_t)gridDim.x * blockDim.x;
    for (; i < n4; i += stride) {
        float4 x = ((const float4*)src)[i];
        s16x4 y;
        y.x = f2bf(x.x); y.y = f2bf(x.y); y.z = f2bf(x.z); y.w = f2bf(x.w);
        ((s16x4*)dst)[i] = y;
    }
}

// ---------------- fused e kernel: 256x256 tile, 8-wave, 4-phase pipelined -------------
// e[b][s] = sum_d w[d]*tanh(hp[b,d] + (V @ U^T)[s,d])
// Block: 512 thr (8 waves, 2(M) x 4(N)), per-wave output 128(s) x 64(d).
// Per block: s-tile of 256 rows, dt-loop over 4 d-slabs of 256 -> all 1024 d in-block,
// e written directly (no partials). Grid (S/256=8, B=32) = 256 blocks = 1/CU.
// K-loop: BK=64, LDS double-buffer (128 KiB), raw s_barrier phases, vmcnt(0) once
// per K-tile (prefetch issued 3 phases earlier -> latency covered), setprio on MFMA.
// LDS swizzle: LDS[r][granule c] holds global chunk c ^ (r&7); staged via pre-swizzled
// per-lane GLOBAL address (linear LDS dest, global_load_lds-safe), read with same XOR.
constexpr int BM_E = 256;
constexpr int BK_E = 64;
constexpr int NT_E = VL_ / BK_E;   // 16 K-tiles per d-slab

__global__ __launch_bounds__(512, 2) void e_kernel_8ph(const short* __restrict__ Vm,
                                                       const short* __restrict__ Um,
                                                       const float* __restrict__ hp,
                                                       const float* __restrict__ ww,
                                                       float* __restrict__ e) {
    __shared__ short Al[2][BM_E][BK_E];   // 64 KiB
    __shared__ short Bl[2][BM_E][BK_E];   // 64 KiB

    const int tid  = threadIdx.x;
    const int wave = tid >> 6, lane = tid & 63;
    const int wm = wave >> 2, wn = wave & 3;      // 2 x 4 wave grid
    const int col = lane & 15, quad = lane >> 4;
    const int rx  = col & 7;                      // read-side swizzle key (== row&7)
    const int s0 = blockIdx.x * BM_E;
    const int b  = blockIdx.y;

    // staging map: lane i covers LDS row (base + i/8), granule i&7 of a 128B row.
    // source chunk pre-swizzled so LDS[r][c] = global chunk c ^ (r&7).
    const int srow   = lane >> 3;                 // 0..7
    const int schunk = (lane & 7) ^ srow;

    const short* gA = Vm + ((size_t)b * S_ + s0 + wave * 8 + srow) * VL_ + schunk * 8;
    const short* gB = Um + (size_t)(wave * 8 + srow) * VL_ + schunk * 8;

    float ep[8][4];   // e partials per (tm, reg), accumulated over all 4 d-slabs
#pragma unroll
    for (int i = 0; i < 8; i++)
#pragma unroll
        for (int j = 0; j < 4; j++) ep[i][j] = 0.0f;

    for (int dt = 0; dt < 4; ++dt) {
        const int d0 = dt * 256;

        f32x4 acc[8][4];
        f32x4 zero = {0.f, 0.f, 0.f, 0.f};
#pragma unroll
        for (int i = 0; i < 8; i++)
#pragma unroll
            for (int j = 0; j < 4; j++) acc[i][j] = zero;

        // prologue: stage K-tile 0 into buffer 0 (A: 4 rounds, B: 4 rounds)
#pragma unroll
        for (int r = 0; r < 4; ++r) {
            async_cp16(gA + (size_t)(r * 64) * VL_, &Al[0][r * 64 + wave * 8][0]);
            async_cp16(gB + ((size_t)(d0 + r * 64)) * VL_, &Bl[0][r * 64 + wave * 8][0]);
        }
        asm volatile("s_waitcnt vmcnt(0)" ::: "memory");
        __builtin_amdgcn_s_barrier();

        for (int t = 0; t < NT_E; ++t) {
            const int c = t & 1;
            s16x8 b8[4][2];
            s16x8 a8[2][2];
#pragma unroll
            for (int p = 0; p < 4; ++p) {
                // phase p computes acc quadrant tm = {2p, 2p+1} over full BK=64
#pragma unroll
                for (int i = 0; i < 2; ++i)
#pragma unroll
                    for (int kk = 0; kk < 2; ++kk)
                        a8[i][kk] = *(const s16x8*)&Al[c][wm * 128 + (2 * p + i) * 16 + col]
                                                        [((((kk << 2) | quad) ^ rx) << 3)];
                if (p == 0) {
#pragma unroll
                    for (int tn = 0; tn < 4; ++tn)
#pragma unroll
                        for (int kk = 0; kk < 2; ++kk)
                            b8[tn][kk] = *(const s16x8*)&Bl[c][wn * 64 + tn * 16 + col]
                                                             [((((kk << 2) | quad) ^ rx) << 3)];
                }
                // prefetch next K-tile into the other buffer (issue-early, wait-late)
                if (p == 0 && t + 1 < NT_E) {
                    const short* g = gA + (size_t)(t + 1) * BK_E;
#pragma unroll
                    for (int r = 0; r < 4; ++r)
                        async_cp16(g + (size_t)(r * 64) * VL_, &Al[c ^ 1][r * 64 + wave * 8][0]);
                }
                if (p == 1 && t + 1 < NT_E) {
                    const short* g = gB + (size_t)d0 * VL_ + (size_t)(t + 1) * BK_E;
#pragma unroll
                    for (int r = 0; r < 4; ++r)
                        async_cp16(g + (size_t)(r * 64) * VL_, &Bl[c ^ 1][r * 64 + wave * 8][0]);
                }
                __builtin_amdgcn_s_barrier();
                __builtin_amdgcn_s_setprio(1);
#pragma unroll
                for (int kk = 0; kk < 2; ++kk)
#pragma unroll
                    for (int i = 0; i < 2; ++i)
#pragma unroll
                        for (int tn = 0; tn < 4; ++tn)
                            acc[2 * p + i][tn] = __builtin_amdgcn_mfma_f32_16x16x32_bf16(
                                a8[i][kk], b8[tn][kk], acc[2 * p + i][tn], 0, 0, 0);
                __builtin_amdgcn_s_setprio(0);
                if (p == 3)
                    asm volatile("s_waitcnt vmcnt(0)" ::: "memory");  // next tile landed
                __builtin_amdgcn_s_barrier();
            }
        }

        // fold this 256-d slab into ep. C/D layout: col=lane&15 (d), row=quad*4+reg (s).
        float wv[4], hv[4];
#pragma unroll
        for (int tn = 0; tn < 4; ++tn) {
            int d = d0 + wn * 64 + tn * 16 + col;
            wv[tn] = ww[d];
            hv[tn] = hp[(size_t)b * HID_ + d];
        }
#pragma unroll
        for (int tm = 0; tm < 8; ++tm)
#pragma unroll
            for (int reg = 0; reg < 4; ++reg)
#pragma unroll
                for (int tn = 0; tn < 4; ++tn)
                    ep[tm][reg] += wv[tn] * fast_tanh(hv[tn] + acc[tm][tn][reg]);
    }

    // final reduction: 16 cols within wave, then the 4 wn-waves via LDS (alias Al,
    // safe: all waves are past the last K-loop barrier, no Al reads remain).
    float* eb = (float*)&Al[0][0][0];   // 4 x 256 floats = 4 KiB
#pragma unroll
    for (int tm = 0; tm < 8; ++tm)
#pragma unroll
        for (int reg = 0; reg < 4; ++reg) {
            float p = ep[tm][reg];
            p += __shfl_xor(p, 1);
            p += __shfl_xor(p, 2);
            p += __shfl_xor(p, 4);
            p += __shfl_xor(p, 8);
            if (col == 0)
                eb[wn * 256 + wm * 128 + tm * 16 + quad * 4 + reg] = p;
        }
    __syncthreads();
    if (tid < 256)
        e[(size_t)b * S_ + s0 + tid] =
            eb[tid] + eb[256 + tid] + eb[512 + tid] + eb[768 + tid];
}

// ---------------- fallback fused e kernel (fp32 inputs, convert-in-staging) ----------
__global__ __launch_bounds__(256) void e_kernel_f32(const float* __restrict__ Vm,
                                                    const float* __restrict__ Um,
                                                    const float* __restrict__ hp,
                                                    const float* __restrict__ ww,
                                                    float* __restrict__ e) {
    __shared__ short As[128][40];
    __shared__ short Bs[128][40];
    int tid = threadIdx.x;
    int b  = blockIdx.z;
    int d0 = blockIdx.x * 128;
    int s0 = blockIdx.y * 128;
    int wave = tid >> 6, lane = tid & 63;
    int wm = wave >> 1, wn = wave & 1;
    int col = lane & 15, quad = lane >> 4;

    f32x4 zero = {0.f, 0.f, 0.f, 0.f};
    f32x4 acc[4][4];
#pragma unroll
    for (int i = 0; i < 4; i++)
#pragma unroll
        for (int j = 0; j < 4; j++) acc[i][j] = zero;

    const float* Abase = Vm + ((size_t)b * S_ + s0) * (size_t)VL_;
    const float* Bbase = Um + (size_t)d0 * (size_t)VL_;

    for (int k0 = 0; k0 < VL_; k0 += 32) {
        int k4 = tid & 7, rb = tid >> 3;
#pragma unroll
        for (int i = 0; i < 4; i++) {
            int r = rb + 32 * i;
            float4 x = *(const float4*)(Abase + (size_t)r * VL_ + k0 + k4 * 4);
            s16x4 ya; ya.x = f2bf(x.x); ya.y = f2bf(x.y); ya.z = f2bf(x.z); ya.w = f2bf(x.w);
            *(s16x4*)&As[r][k4 * 4] = ya;
            float4 y = *(const float4*)(Bbase + (size_t)r * VL_ + k0 + k4 * 4);
            s16x4 yb; yb.x = f2bf(y.x); yb.y = f2bf(y.y); yb.z = f2bf(y.z); yb.w = f2bf(y.w);
            *(s16x4*)&Bs[r][k4 * 4] = yb;
        }
        __syncthreads();
        s16x8 a8[4], b8[4];
#pragma unroll
        for (int tm = 0; tm < 4; tm++)
            a8[tm] = *(const s16x8*)&As[wm * 64 + tm * 16 + col][quad * 8];
#pragma unroll
        for (int tn = 0; tn < 4; tn++)
            b8[tn] = *(const s16x8*)&Bs[wn * 64 + tn * 16 + col][quad * 8];
#pragma unroll
        for (int tm = 0; tm < 4; tm++)
#pragma unroll
            for (int tn = 0; tn < 4; tn++)
                acc[tm][tn] = __builtin_amdgcn_mfma_f32_16x16x32_bf16(
                    a8[tm], b8[tn], acc[tm][tn], 0, 0, 0);
        __syncthreads();
    }

    float wv[4], hv[4];
#pragma unroll
    for (int tn = 0; tn < 4; tn++) {
        int d = d0 + wn * 64 + tn * 16 + col;
        wv[tn] = ww[d];
        hv[tn] = hp[(size_t)b * HID_ + d];
    }
#pragma unroll
    for (int tm = 0; tm < 4; tm++) {
#pragma unroll
        for (int reg = 0; reg < 4; reg++) {
            float p = 0.0f;
#pragma unroll
            for (int tn = 0; tn < 4; tn++)
                p += wv[tn] * fast_tanh(hv[tn] + acc[tm][tn][reg]);
            p += __shfl_xor(p, 1);
            p += __shfl_xor(p, 2);
            p += __shfl_xor(p, 4);
            p += __shfl_xor(p, 8);
            if (col == 0) {
                int s = s0 + wm * 64 + tm * 16 + quad * 4 + reg;
                atomicAdd(&e[(size_t)b * S_ + s], p);
            }
        }
    }
}

// ---------------- softmax over s: beta = softmax(e), one block per b ------------------
// nparts: how many e-partial slices to sum (1 for 8ph path, 1 for fallback).
__global__ __launch_bounds__(256) void softmax_kernel(const float* __restrict__ epart,
                                                      float* __restrict__ beta,
                                                      int nparts) {
    int b = blockIdx.x, tid = threadIdx.x;
    const float* r0 = epart + (size_t)b * S_;
    const float* r1 = epart + ((size_t)B_ + b) * S_;
    float v[8];
    float m = -1e30f;
#pragma unroll
    for (int i = 0; i < 8; i++) {
        int idx = tid + i * 256;
        v[i] = r0[idx] + (nparts > 1 ? r1[idx] : 0.0f);
        m = fmaxf(m, v[i]);
    }
#pragma unroll
    for (int o = 32; o; o >>= 1) m = fmaxf(m, __shfl_xor(m, o));
    __shared__ float rm[4], rs[4];
    int wave = tid >> 6, lane = tid & 63;
    if (lane == 0) rm[wave] = m;
    __syncthreads();
    m = fmaxf(fmaxf(rm[0], rm[1]), fmaxf(rm[2], rm[3]));
    float s = 0.0f;
#pragma unroll
    for (int i = 0; i < 8; i++) { v[i] = __expf(v[i] - m); s += v[i]; }
#pragma unroll
    for (int o = 32; o; o >>= 1) s += __shfl_xor(s, o);
    if (lane == 0) rs[wave] = s;
    __syncthreads();
    s = rs[0] + rs[1] + rs[2] + rs[3];
    float inv = 1.0f / s;
#pragma unroll
    for (int i = 0; i < 8; i++) beta[(size_t)b * S_ + tid + i * 256] = v[i] * inv;
}

// ---------------- out partials: opart[b][sc][v] = sum_{s in chunk} beta*V  ------------
__global__ __launch_bounds__(256) void out_kernel_bf16(const float* __restrict__ beta,
                                                       const short* __restrict__ Vb16,
                                                       float* __restrict__ opart) {
    int b = blockIdx.x, sc = blockIdx.y;    // grid (B, 16), s-chunk = 128
    int v4 = threadIdx.x;
    const short* Vp = Vb16 + ((size_t)b * S_ + (size_t)sc * 128) * VL_;
    const float* bb = beta + (size_t)b * S_ + (size_t)sc * 128;
    float ax = 0.f, ay = 0.f, az = 0.f, aw = 0.f;
    for (int s = 0; s < 128; s++) {
        float w = bb[s];
        s16x4 x = *(const s16x4*)(Vp + (size_t)s * VL_ + v4 * 4);
        ax += w * bf2f(x.x); ay += w * bf2f(x.y);
        az += w * bf2f(x.z); aw += w * bf2f(x.w);
    }
    float4 r = {ax, ay, az, aw};
    *(float4*)(opart + (((size_t)b * 16 + sc) * VL_) + v4 * 4) = r;
}

// out[b][v] = sum_{sc<16} opart[b][sc][v]
__global__ __launch_bounds__(256) void out_reduce_kernel(const float* __restrict__ opart,
                                                         float* __restrict__ out) {
    int b = blockIdx.x, v4 = threadIdx.x;   // 256 float4 slots = VL
    float4 a = {0.f, 0.f, 0.f, 0.f};
    const float* base = opart + (size_t)b * 16 * VL_;
#pragma unroll
    for (int sc = 0; sc < 16; sc++) {
        float4 x = *(const float4*)(base + (size_t)sc * VL_ + v4 * 4);
        a.x += x.x; a.y += x.y; a.z += x.z; a.w += x.w;
    }
    *(float4*)(out + (size_t)b * VL_ + v4 * 4) = a;
}

__global__ __launch_bounds__(256) void out_kernel_f32(const float* __restrict__ beta,
                                                      const float* __restrict__ V,
                                                      float* __restrict__ out) {
    int b = blockIdx.x, sc = blockIdx.y;
    int v4 = threadIdx.x;
    const float* Vb = V + ((size_t)b * S_ + (size_t)sc * 128) * VL_;
    const float* bb = beta + (size_t)b * S_ + (size_t)sc * 128;
    float ax = 0.f, ay = 0.f, az = 0.f, aw = 0.f;
    for (int s = 0; s < 128; s++) {
        float w = bb[s];
        float4 x = *(const float4*)(Vb + (size_t)s * VL_ + v4 * 4);
        ax += w * x.x; ay += w * x.y; az += w * x.z; aw += w * x.w;
    }
    float* o = out + (size_t)b * VL_ + v4 * 4;
    atomicAdd(o + 0, ax);
    atomicAdd(o + 1, ay);
    atomicAdd(o + 2, az);
    atomicAdd(o + 3, aw);
}

extern "C" void kernel_launch(void* const* d_in, const int* in_sizes, int n_in,
                              void* d_out, int out_size, void* d_ws, size_t ws_size,
                              hipStream_t stream) {
    const float* h  = (const float*)d_in[0];
    const float* V  = (const float*)d_in[1];
    const float* Ww = (const float*)d_in[2];
    const float* Wb = (const float*)d_in[3];
    const float* Uw = (const float*)d_in[4];
    const float* ww = (const float*)d_in[5];
    float* out = (float*)d_out;

    char* ws = (char*)d_ws;
    float* hp    = (float*)ws;                              // 128 KiB @ 0
    float* epart = (float*)(ws + 131072);                   // e buffer (512 KiB region)
    float* beta  = (float*)(ws + 131072 + 524288);          // 32*2048*4 = 256 KiB
    float* opart = (float*)(ws + 131072 + 524288 + 262144); // 32*16*1024*4 = 2 MiB
    size_t fixed = 131072 + 524288 + 262144 + 2097152;      // 2.94 MiB
    short* Vb16 = (short*)(ws + fixed);                     // 128 MiB
    short* Ub16 = Vb16 + (size_t)B_ * S_ * VL_;             // 2 MiB
    size_t need = fixed + ((size_t)B_ * S_ * VL_ + (size_t)HID_ * VL_) * 2;
    bool bf16path = (ws_size >= need);

    hproj_kernel<<<dim3(HID_ / 4), 256, 0, stream>>>(h, Ww, Wb, hp);

    if (bf16path) {
        cvt_kernel<<<4096, 256, 0, stream>>>(V, Vb16, (size_t)B_ * S_ * VL_ / 4);
        cvt_kernel<<<256, 256, 0, stream>>>(Uw, Ub16, (size_t)HID_ * VL_ / 4);
        e_kernel_8ph<<<dim3(S_ / BM_E, B_), 512, 0, stream>>>(Vb16, Ub16, hp, ww, epart);
        softmax_kernel<<<B_, 256, 0, stream>>>(epart, beta, 1);
        out_kernel_bf16<<<dim3(B_, S_ / 128), 256, 0, stream>>>(beta, Vb16, opart);
        out_reduce_kernel<<<B_, 256, 0, stream>>>(opart, out);
    } else {
        hipMemsetAsync(epart, 0, (size_t)B_ * S_ * 4, stream);
        hipMemsetAsync(out, 0, (size_t)out_size * 4, stream);
        e_kernel_f32<<<dim3(HID_ / 128, S_ / 128, B_), 256, 0, stream>>>(
            V, Uw, hp, ww, epart);
        softmax_kernel<<<B_, 256, 0, stream>>>(epart, beta, 1);
        out_kernel_f32<<<dim3(B_, S_ / 128), 256, 0, stream>>>(beta, V, out);
    }
}